// Round 3
// baseline (1322.080 us; speedup 1.0000x reference)
//
#include <hip/hip_runtime.h>

typedef unsigned short u16;
typedef unsigned int u32;
typedef __attribute__((ext_vector_type(8))) short bf16x8;
typedef __attribute__((ext_vector_type(4))) float f32x4;
typedef __attribute__((ext_vector_type(16))) float f32x16;
typedef __attribute__((ext_vector_type(8))) u16 u16x8;

__device__ __forceinline__ u16 f2bf(float f) {
  u32 u = __float_as_uint(f);
  return (u16)((u + 0x7fffu + ((u >> 16) & 1u)) >> 16);
}

__device__ __forceinline__ void glds16(const void* g, void* l) {
  __builtin_amdgcn_global_load_lds(
      (const __attribute__((address_space(1))) unsigned int*)g,
      (__attribute__((address_space(3))) unsigned int*)l, 16, 0, 0);
}

// unpack 16 bf16 -> 16 f32 (two 16-B loads)
__device__ __forceinline__ f32x16 unpack16(const u16* p) {
  uint4 a = *(const uint4*)p, b = *(const uint4*)(p + 8);
  f32x16 r;
  r[0]  = __uint_as_float(a.x << 16); r[1]  = __uint_as_float(a.x & 0xffff0000u);
  r[2]  = __uint_as_float(a.y << 16); r[3]  = __uint_as_float(a.y & 0xffff0000u);
  r[4]  = __uint_as_float(a.z << 16); r[5]  = __uint_as_float(a.z & 0xffff0000u);
  r[6]  = __uint_as_float(a.w << 16); r[7]  = __uint_as_float(a.w & 0xffff0000u);
  r[8]  = __uint_as_float(b.x << 16); r[9]  = __uint_as_float(b.x & 0xffff0000u);
  r[10] = __uint_as_float(b.y << 16); r[11] = __uint_as_float(b.y & 0xffff0000u);
  r[12] = __uint_as_float(b.z << 16); r[13] = __uint_as_float(b.z & 0xffff0000u);
  r[14] = __uint_as_float(b.w << 16); r[15] = __uint_as_float(b.w & 0xffff0000u);
  return r;
}

// ---------------------------------------------------------------------------
// convert edge f32 [131072][256] -> bf16 tiled+swizzled [1024 rt][4 kc][128 r][64 k]
// element (r,k) stored at u16 idx r*64 + (k ^ ((r&7)*8)). NT loads: read-once
// stream, keep L3 free for E1/E2 (re-read 3x by fused_gate).
// ---------------------------------------------------------------------------
__global__ __launch_bounds__(256) void convert_edge(
    const float* __restrict__ src, u16* __restrict__ dst) {
  int g = blockIdx.x * 256 + threadIdx.x;
  int kg = g & 7, r = (g >> 3) & 127, kc = (g >> 10) & 3, rt = g >> 12;
  const float* s = src + ((long)(rt * 128 + r) * 256 + kc * 64 + kg * 8);
  f32x4 a = __builtin_nontemporal_load((const f32x4*)s);
  f32x4 b = __builtin_nontemporal_load((const f32x4*)(s + 4));
  u16x8 h;
  h[0] = f2bf(a[0]); h[1] = f2bf(a[1]); h[2] = f2bf(a[2]); h[3] = f2bf(a[3]);
  h[4] = f2bf(b[0]); h[5] = f2bf(b[1]); h[6] = f2bf(b[2]); h[7] = f2bf(b[3]);
  u16* d = dst + (long)rt * 65536 + kc * 16384 + r * 64 + (kg ^ (r & 7)) * 8;
  __builtin_nontemporal_store(h, (u16x8*)d);
}

// ---------------------------------------------------------------------------
// Edge GEMM: E[131072 x 512] = A_tiled(bf16) * Bt_tiled(bf16)^T, K=256.
// 128x128 tile, 4 waves, global_load_lds, swizzled LDS.
// XCD-aware block swizzle: the 4 ct-blocks of one rt land on the SAME XCD in
// adjacent rounds -> A tile served from that XCD's L2 (1x HBM not 4x).
// ---------------------------------------------------------------------------
__global__ __launch_bounds__(256) void gemm_edge(
    const u16* __restrict__ A, const u16* __restrict__ Bt,
    u16* __restrict__ E) {
  __shared__ __align__(16) u16 Asm[8192];
  __shared__ __align__(16) u16 Bsm[8192];
  const int tid = threadIdx.x, lane = tid & 63, w = tid >> 6;
  const int m = lane & 15, q = lane >> 4;
  const int p = blockIdx.x;
  const int sidx = p >> 3, xcd = p & 7;
  const int rt = (sidx >> 2) * 8 + xcd;   // same rt for 4 adjacent same-XCD slots
  const int ct = sidx & 3;
  const int wrow = (w & 1) * 64, wcol = (w >> 1) * 64;
  const char* Ab = (const char*)A + (long)rt * 131072;
  const char* Bb = (const char*)Bt + (long)ct * 65536;
  f32x4 acc[4][4];
#pragma unroll
  for (int r = 0; r < 4; ++r)
#pragma unroll
    for (int c = 0; c < 4; ++c) acc[r][c] = (f32x4){0.f, 0.f, 0.f, 0.f};

  for (int kc = 0; kc < 4; ++kc) {
#pragma unroll
    for (int t = 0; t < 4; ++t) {
      glds16(Ab + kc * 32768 + t * 4096 + tid * 16,
             (char*)Asm + t * 4096 + tid * 16);
      glds16(Bb + kc * 16384 + t * 4096 + tid * 16,
             (char*)Bsm + t * 4096 + tid * 16);
    }
    __syncthreads();
#pragma unroll
    for (int s = 0; s < 2; ++s) {
      const int ko2 = (s * 32 + q * 8) * 2;
      bf16x8 av[4], bv[4];
#pragma unroll
      for (int r = 0; r < 4; ++r) {
        int row = wrow + r * 16 + m;
        av[r] = *(const bf16x8*)((const char*)Asm + row * 128 +
                                 (ko2 ^ ((row & 7) * 16)));
      }
#pragma unroll
      for (int c = 0; c < 4; ++c) {
        int col = wcol + c * 16 + m;
        bv[c] = *(const bf16x8*)((const char*)Bsm + col * 128 +
                                 (ko2 ^ ((col & 7) * 16)));
      }
#pragma unroll
      for (int r = 0; r < 4; ++r)
#pragma unroll
        for (int c = 0; c < 4; ++c)
          acc[r][c] = __builtin_amdgcn_mfma_f32_16x16x32_bf16(
              av[r], bv[c], acc[r][c], 0, 0, 0);
    }
    __syncthreads();
  }
#pragma unroll
  for (int r = 0; r < 4; ++r)
#pragma unroll
    for (int c = 0; c < 4; ++c)
#pragma unroll
      for (int g = 0; g < 4; ++g) {
        long gr = (long)rt * 128 + wrow + r * 16 + q * 4 + g;
        int gc = ct * 128 + wcol + c * 16 + m;
        E[gr * 512 + gc] = f2bf(acc[r][c][g]);
      }
}

// ---------------------------------------------------------------------------
// Generic small GEMM (f32 A): C[M x Ntot] = A[M x K] * Bt[Ntot x K]^T
// ROWS=64 tile x 256 cols, 4 waves (each 64x64).
// MODE 0: f32 C. MODE 1: bf16 C. MODE 2: split — gc<256 -> relu to Cv(f32),
// gc>=256 -> raw to C2 (compact 256-wide).
// ---------------------------------------------------------------------------
template<int K, int MODE>
__global__ __launch_bounds__(256) void gemm_mfma(
    const float* __restrict__ A, const u16* __restrict__ Bt,
    void* __restrict__ Cv, float* __restrict__ C2, int Ntot) {
  constexpr int LD = 72;
  __shared__ __align__(16) u16 Asm[64 * LD];
  __shared__ __align__(16) u16 Bsm[256 * LD];
  const int tid = threadIdx.x;
  const int lane = tid & 63;
  const int w = tid >> 6;
  const int m = lane & 15;
  const int q = lane >> 4;
  const int wcol = w * 64;
  const long rowbase = (long)blockIdx.x * 64;
  const long colbase = (long)blockIdx.y * 256;
  f32x4 acc[4][4];
#pragma unroll
  for (int r = 0; r < 4; ++r)
#pragma unroll
    for (int c = 0; c < 4; ++c) acc[r][c] = (f32x4){0.f, 0.f, 0.f, 0.f};

  for (int kc = 0; kc < K / 64; ++kc) {
    const int kb = kc * 64;
#pragma unroll
    for (int it = 0; it < 4; ++it) {
      int f = it * 256 + tid;
      int r = f >> 4, c4 = (f & 15) * 4;
      float4 v = *(const float4*)(A + (rowbase + r) * K + kb + c4);
      ushort4 h;
      h.x = f2bf(v.x); h.y = f2bf(v.y); h.z = f2bf(v.z); h.w = f2bf(v.w);
      *(ushort4*)&Asm[r * LD + c4] = h;
    }
#pragma unroll
    for (int it = 0; it < 8; ++it) {
      int f = it * 256 + tid;
      int c = f >> 3, k8 = (f & 7) * 8;
      *(uint4*)&Bsm[c * LD + k8] =
          *(const uint4*)(Bt + (colbase + c) * K + kb + k8);
    }
    __syncthreads();
#pragma unroll
    for (int s = 0; s < 2; ++s) {
      const int ko = s * 32 + q * 8;
      bf16x8 av[4], bv[4];
#pragma unroll
      for (int r = 0; r < 4; ++r)
        av[r] = *(const bf16x8*)&Asm[(r * 16 + m) * LD + ko];
#pragma unroll
      for (int c = 0; c < 4; ++c)
        bv[c] = *(const bf16x8*)&Bsm[(wcol + c * 16 + m) * LD + ko];
#pragma unroll
      for (int r = 0; r < 4; ++r)
#pragma unroll
        for (int c = 0; c < 4; ++c)
          acc[r][c] = __builtin_amdgcn_mfma_f32_16x16x32_bf16(
              av[r], bv[c], acc[r][c], 0, 0, 0);
    }
    __syncthreads();
  }
#pragma unroll
  for (int r = 0; r < 4; ++r)
#pragma unroll
    for (int c = 0; c < 4; ++c)
#pragma unroll
      for (int g = 0; g < 4; ++g) {
        long gr = rowbase + r * 16 + q * 4 + g;
        long gc = colbase + wcol + c * 16 + m;
        float v = acc[r][c][g];
        if (MODE == 1)      ((u16*)Cv)[gr * Ntot + gc] = f2bf(v);
        else if (MODE == 0) ((float*)Cv)[gr * Ntot + gc] = v;
        else {
          if (gc < 256) ((float*)Cv)[gr * 256 + gc] = fmaxf(v, 0.f);
          else          C2[gr * 256 + gc - 256] = v;
        }
      }
}

// ---------------------------------------------------------------------------
// Weight tables. BtE1/BtE2: tiled+swizzled [4 ct][4 kc][128 c][64 k].
// BtW0 [512][256], BtLoop [1536][256], BtFc3 [256][512].
// ---------------------------------------------------------------------------
__global__ __launch_bounds__(256) void prep_bt(
    const float* __restrict__ weight, const float* __restrict__ align_lin,
    const float* __restrict__ fuse1_w, const float* __restrict__ fuse2_w,
    const float* __restrict__ fc1_w0, const float* __restrict__ fc2_w0,
    const float* __restrict__ fc3_w,
    u16* BtE1, u16* BtE2, u16* BtW0, u16* BtLoop, u16* BtFc3) {
  int g = blockIdx.x * 256 + threadIdx.x;  // 0..917503
  if (g < 262144) {
    int t = g & 131071;
    int col = t >> 8, k = t & 255;
    float v;
    if (g < 131072)
      v = (col < 256) ? fuse1_w[(256 + k) * 256 + col]
                      : fc1_w0[(512 + k) * 256 + (col - 256)];
    else
      v = (col < 256) ? fuse2_w[(256 + k) * 256 + col]
                      : fc2_w0[(512 + k) * 256 + (col - 256)];
    int ct = col >> 7, cc = col & 127, kc = k >> 6, kk = k & 63;
    u16* dst = (g < 131072) ? BtE1 : BtE2;
    dst[ct * 32768 + kc * 8192 + cc * 64 + (kk ^ ((cc & 7) * 8))] = f2bf(v);
  } else if (g < 393216) {
    int t = g - 262144;
    int c = t >> 8, k = t & 255;
    float v = (c < 256) ? weight[k * 256 + c] : align_lin[k * 256 + (c - 256)];
    BtW0[t] = f2bf(v);
  } else if (g < 786432) {
    int t = g - 393216;
    int c = t >> 8, k = t & 255;
    int seg = c >> 8, cc = c & 255;
    float v;
    if      (seg == 0) v = fuse1_w[k * 256 + cc];
    else if (seg == 1) v = fuse2_w[k * 256 + cc];
    else if (seg == 2) v = fc1_w0[k * 256 + cc];
    else if (seg == 3) v = fc1_w0[(256 + k) * 256 + cc];
    else if (seg == 4) v = fc2_w0[k * 256 + cc];
    else               v = fc2_w0[(256 + k) * 256 + cc];
    BtLoop[t] = f2bf(v);
  } else {
    int t = g - 786432;
    int c = t >> 9, k = t & 511;
    BtFc3[t] = f2bf(fc3_w[k * 256 + c]);
  }
}

// ---------------------------------------------------------------------------
// SelfAlignment. 256 threads: phase 1 (tid<128) logits+softmax, phase 2 all
// 256 threads do the p @ text matvec (one d each).
// ---------------------------------------------------------------------------
__global__ __launch_bounds__(256) void align_kernel(
    const float* __restrict__ text, const float* __restrict__ Ta,
    const float* __restrict__ textmask, const float* __restrict__ align_bias,
    float* __restrict__ outss) {
  const int bi = blockIdx.x;
  const int b = bi >> 7;
  const int tid = threadIdx.x;
  __shared__ float ta[256];
  __shared__ float pr[128];
  __shared__ float red[128];
  ta[tid] = Ta[(long)bi * 256 + tid];
  __syncthreads();
  float e = 0.f;
  if (tid < 128) {
    const float* trow = text + (long)(b * 128 + tid) * 256;
    float dot = 0.f;
    for (int d = 0; d < 256; d += 4) {
      float4 t4 = *(const float4*)(trow + d);
      dot += t4.x * ta[d] + t4.y * ta[d + 1] + t4.z * ta[d + 2] + t4.w * ta[d + 3];
    }
    float logit = dot + (1.0f - textmask[b * 128 + tid]) * -1e20f;
    pr[tid] = logit;
    red[tid] = logit;
  }
  __syncthreads();
  for (int off = 64; off; off >>= 1) {
    if (tid < off) red[tid] = fmaxf(red[tid], red[tid + off]);
    __syncthreads();
  }
  float mx = red[0];
  __syncthreads();
  if (tid < 128) {
    e = __expf(pr[tid] - mx);
    red[tid] = e;
  }
  __syncthreads();
  for (int off = 64; off; off >>= 1) {
    if (tid < off) red[tid] += red[tid + off];
    __syncthreads();
  }
  float inv = 1.0f / red[0];
  __syncthreads();
  if (tid < 128) pr[tid] = e * inv;
  __syncthreads();
  const float mi = textmask[bi];
  float s = 0.f;
  const float* tcol = text + (long)b * 32768 + tid;
#pragma unroll 4
  for (int j = 0; j < 128; ++j) s += pr[j] * tcol[j * 256];
  outss[(long)bi * 256 + tid] = s * mi + align_bias[tid];
}

// ---------------------------------------------------------------------------
// Fused gate/aggregate partials. grid 4096: bi = blk>>2, jc = blk&3 (32 j's).
// 128 thr = 2 waves; wave w: j = jc*32 + w*16 + t*4 + g16, lane owns 16 d's.
// Writes partial sums to OUP[blk][512], denominators to DAP[blk][2].
// ---------------------------------------------------------------------------
__global__ __launch_bounds__(128, 4) void fused_gate(
    const u16* __restrict__ E1, const u16* __restrict__ E2,
    const float* __restrict__ P, const float* __restrict__ adj1,
    const float* __restrict__ adj2, const float* __restrict__ fc1w1,
    const float* __restrict__ fc1b1, const float* __restrict__ fc2w1,
    const float* __restrict__ fc2b1, float* __restrict__ OUP,
    float* __restrict__ DAP) {
  const int tid = threadIdx.x, lane = tid & 63, w = tid >> 6;
  const int g16 = lane >> 4, l16 = lane & 15;
  const int blk = blockIdx.x;
  const int bi = blk >> 2, jc = blk & 3;
  const int b = bi >> 7;
  const int db = l16 * 16;
  const long rowi = (long)bi * 1536;
  const f32x16 w1v = *(const f32x16*)(fc1w1 + db);
  const f32x16 w2v = *(const f32x16*)(fc2w1 + db);
  const f32x16 ti1 = *(const f32x16*)(P + rowi + 512 + db);
  const f32x16 ti2 = *(const f32x16*)(P + rowi + 1024 + db);
  const float b1 = fc1b1[0], b2 = fc2b1[0];
  const long ebase = (long)bi * 65536;
  const int abase = bi * 128;
  f32x16 acc1, acc2;
#pragma unroll
  for (int dd = 0; dd < 16; ++dd) { acc1[dd] = 0.f; acc2[dd] = 0.f; }
  float da1 = 0.f, da2 = 0.f;

#pragma unroll 2
  for (int t = 0; t < 4; ++t) {
    const int j = jc * 32 + w * 16 + t * 4 + g16;
    const long er = ebase + (long)j * 512;
    const long rowj = (long)(b * 128 + j) * 1536;
    f32x16 e1cf = unpack16(E1 + er + 256 + db);
    f32x16 e2cf = unpack16(E2 + er + 256 + db);
    f32x16 tj1 = *(const f32x16*)(P + rowj + 768 + db);
    f32x16 tj2 = *(const f32x16*)(P + rowj + 1280 + db);
    float a1 = adj1[abase + j], a2 = adj2[abase + j];
    float z1 = 0.f, z2 = 0.f;
#pragma unroll
    for (int dd = 0; dd < 16; ++dd) {
      z1 += fmaxf(ti1[dd] + tj1[dd] + e1cf[dd], 0.f) * w1v[dd];
      z2 += fmaxf(ti2[dd] + tj2[dd] + e2cf[dd], 0.f) * w2v[dd];
    }
#pragma unroll
    for (int off = 1; off < 16; off <<= 1) {
      z1 += __shfl_xor(z1, off);
      z2 += __shfl_xor(z2, off);
    }
    float s1 = a1 / (1.f + __expf(-(z1 + b1)));
    float s2 = a2 / (1.f + __expf(-(z2 + b2)));
    f32x16 e1ff = unpack16(E1 + er + db);
    f32x16 e2ff = unpack16(E2 + er + db);
    f32x16 of1 = *(const f32x16*)(P + rowj + db);
    f32x16 of2 = *(const f32x16*)(P + rowj + 256 + db);
#pragma unroll
    for (int dd = 0; dd < 16; ++dd) {
      acc1[dd] += s1 * fmaxf(of1[dd] + e1ff[dd], 0.f);
      acc2[dd] += s2 * fmaxf(of2[dd] + e2ff[dd], 0.f);
    }
    da1 += a1;
    da2 += a2;
  }

  __shared__ float redA[8][260];
  __shared__ float redB[8][260];
  __shared__ float dA[8], dB[8];
  const int pidx = w * 4 + g16;
#pragma unroll
  for (int v = 0; v < 4; ++v) {
    *(float4*)&redA[pidx][db + v * 4] =
        make_float4(acc1[v*4], acc1[v*4+1], acc1[v*4+2], acc1[v*4+3]);
    *(float4*)&redB[pidx][db + v * 4] =
        make_float4(acc2[v*4], acc2[v*4+1], acc2[v*4+2], acc2[v*4+3]);
  }
  if (l16 == 0) { dA[pidx] = da1; dB[pidx] = da2; }
  __syncthreads();
#pragma unroll
  for (int h = 0; h < 2; ++h) {
    int col = h * 128 + tid;
    float o1 = 0.f, o2 = 0.f;
#pragma unroll
    for (int pp = 0; pp < 8; ++pp) {
      o1 += redA[pp][col];
      o2 += redB[pp][col];
    }
    OUP[(long)blk * 512 + col] = o1;
    OUP[(long)blk * 512 + 256 + col] = o2;
  }
  if (tid == 0) {
    float d1 = 0.f, d2 = 0.f;
#pragma unroll
    for (int pp = 0; pp < 8; ++pp) { d1 += dA[pp]; d2 += dB[pp]; }
    DAP[blk * 2] = d1;
    DAP[blk * 2 + 1] = d2;
  }
}

// ---------------------------------------------------------------------------
// Merge the 4 j-chunk partials: OU12[bi][512] = (sum_c OUP)/(1+sum_c DAP)
// ---------------------------------------------------------------------------
__global__ __launch_bounds__(256) void merge_ou(
    const float* __restrict__ OUP, const float* __restrict__ DAP,
    float* __restrict__ OU12) {
  const int bi = blockIdx.x, tid = threadIdx.x;
  const long base = (long)bi * 4 * 512;
  float d1 = 1.f + DAP[bi*8+0] + DAP[bi*8+2] + DAP[bi*8+4] + DAP[bi*8+6];
  float d2 = 1.f + DAP[bi*8+1] + DAP[bi*8+3] + DAP[bi*8+5] + DAP[bi*8+7];
#pragma unroll
  for (int h = 0; h < 2; ++h) {
    int col = h * 256 + tid;
    float o = OUP[base + col] + OUP[base + 512 + col] +
              OUP[base + 1024 + col] + OUP[base + 1536 + col];
    OU12[(long)bi * 512 + col] = o / ((col < 256) ? d1 : d2);
  }
}

// ---------------------------------------------------------------------------
// out = layernorm(relu(Y) + prev + bias) * gamma + beta
// ---------------------------------------------------------------------------
__global__ __launch_bounds__(256) void ln_kernel(
    const float* __restrict__ Y, const float* __restrict__ prev,
    const float* __restrict__ bias, const float* __restrict__ gamma,
    const float* __restrict__ beta, float* __restrict__ dst) {
  const int row = blockIdx.x, tid = threadIdx.x, lane = tid & 63, w = tid >> 6;
  const long idx = (long)row * 256 + tid;
  float v = fmaxf(Y[idx], 0.f) + prev[idx] + bias[tid];
  float s = v;
#pragma unroll
  for (int off = 32; off; off >>= 1) s += __shfl_xor(s, off);
  __shared__ float wsA[4], wsB[4];
  if (lane == 0) wsA[w] = s;
  __syncthreads();
  float mean = (wsA[0] + wsA[1] + wsA[2] + wsA[3]) * (1.0f / 256.0f);
  float c = v - mean;
  float s2 = c * c;
#pragma unroll
  for (int off = 32; off; off >>= 1) s2 += __shfl_xor(s2, off);
  if (lane == 0) wsB[w] = s2;
  __syncthreads();
  float var = (wsB[0] + wsB[1] + wsB[2] + wsB[3]) * (1.0f / 256.0f);
  dst[idx] = c * rsqrtf(var + 1e-5f) * gamma[tid] + beta[tid];
}

// ---------------------------------------------------------------------------
extern "C" void kernel_launch(void* const* d_in, const int* in_sizes, int n_in,
                              void* d_out, int out_size, void* d_ws, size_t ws_size,
                              hipStream_t stream) {
  const float* text      = (const float*)d_in[0];
  const float* adj1      = (const float*)d_in[1];
  const float* adj2      = (const float*)d_in[2];
  const float* edge1     = (const float*)d_in[3];
  const float* edge2     = (const float*)d_in[4];
  const float* textmask  = (const float*)d_in[5];
  const float* weight    = (const float*)d_in[6];
  const float* bias      = (const float*)d_in[7];
  const float* gamma     = (const float*)d_in[8];
  const float* beta      = (const float*)d_in[9];
  const float* fuse1_w   = (const float*)d_in[10];
  const float* fuse2_w   = (const float*)d_in[11];
  const float* fc3_w     = (const float*)d_in[12];
  const float* fc1_w0    = (const float*)d_in[13];
  const float* fc1_w1    = (const float*)d_in[14];
  const float* fc1_b1    = (const float*)d_in[15];
  const float* fc2_w0    = (const float*)d_in[16];
  const float* fc2_w1    = (const float*)d_in[17];
  const float* fc2_b1    = (const float*)d_in[18];
  const float* align_lin = (const float*)d_in[19];
  const float* align_bias= (const float*)d_in[20];
  float* outF = (float*)d_out;  // out: [0,262144), outss: [262144,524288)

  char* w8 = (char*)d_ws;
  u16* Ax   = (u16*)w8;                       // 64 MB region (dual-use)
  u16* E1   = (u16*)(w8 + 67108864);          // 128 MB
  u16* E2   = (u16*)(w8 + 201326592);         // 128 MB
  u16* BtE1 = (u16*)(w8 + 335544320);
  u16* BtE2 = BtE1 + 131072;
  u16* BtW0 = BtE2 + 131072;
  u16* BtLoop = BtW0 + 131072;                // 1536 x 256
  u16* BtFc3  = BtLoop + 393216;              // 256 x 512
  // f32 buffers inside the Ax region (dead after edge GEMMs)
  float* P    = (float*)w8;                   // 1024 x 1536 (6 MB)
  float* Ta   = P + 1572864;                  // 1024 x 256 (1 MB)
  float* OU12 = Ta + 262144;                  // 1024 x 512 (2 MB)
  float* outb = OU12 + 524288;                // 1024 x 256 (1 MB)
  float* Yb   = outb + 262144;                // 1024 x 256 (1 MB)
  float* OUP  = Yb + 262144;                  // 4096 x 512 (8 MB)
  float* DAP  = OUP + 2097152;                // 4096 x 2

  // 1) weight tables
  prep_bt<<<3584, 256, 0, stream>>>(weight, align_lin, fuse1_w, fuse2_w,
                                    fc1_w0, fc2_w0, fc3_w,
                                    BtE1, BtE2, BtW0, BtLoop, BtFc3);
  // 2) edge projections (loop-invariant)
  convert_edge<<<16384, 256, 0, stream>>>(edge1, Ax);
  gemm_edge<<<4096, 256, 0, stream>>>(Ax, BtE1, E1);
  convert_edge<<<16384, 256, 0, stream>>>(edge2, Ax);
  gemm_edge<<<4096, 256, 0, stream>>>(Ax, BtE2, E2);
  // 3) split GEMM: outb = relu(text@weight), Ta = text@align_lin
  gemm_mfma<256, 2><<<dim3(16, 2), 256, 0, stream>>>(text, BtW0, outb, Ta, 512);
  // 4) self-alignment -> outss
  align_kernel<<<1024, 256, 0, stream>>>(text, Ta, textmask, align_bias,
                                         outF + 262144);
  // 5) K = 3 GCN iterations
  for (int it = 0; it < 3; ++it) {
    gemm_mfma<256, 0><<<dim3(16, 6), 256, 0, stream>>>(outb, BtLoop, P, nullptr, 1536);
    fused_gate<<<4096, 128, 0, stream>>>(E1, E2, P, adj1, adj2, fc1_w1, fc1_b1,
                                         fc2_w1, fc2_b1, OUP, DAP);
    merge_ou<<<1024, 256, 0, stream>>>(OUP, DAP, OU12);
    gemm_mfma<512, 0><<<dim3(16, 1), 256, 0, stream>>>(OU12, BtFc3, Yb, nullptr, 256);
    ln_kernel<<<1024, 256, 0, stream>>>(Yb, outb, bias, gamma, beta,
                                        (it == 2) ? outF : outb);
  }
}

// Round 4
// 792.248 us; speedup vs baseline: 1.6688x; 1.6688x over previous
//
#include <hip/hip_runtime.h>

typedef unsigned short u16;
typedef unsigned int u32;
typedef __attribute__((ext_vector_type(8))) short bf16x8;
typedef __attribute__((ext_vector_type(4))) float f32x4;
typedef __attribute__((ext_vector_type(16))) float f32x16;
typedef __attribute__((ext_vector_type(8))) u16 u16x8;

__device__ __forceinline__ u16 f2bf(float f) {
  u32 u = __float_as_uint(f);
  return (u16)((u + 0x7fffu + ((u >> 16) & 1u)) >> 16);
}

__device__ __forceinline__ void glds16(const void* g, void* l) {
  __builtin_amdgcn_global_load_lds(
      (const __attribute__((address_space(1))) unsigned int*)g,
      (__attribute__((address_space(3))) unsigned int*)l, 16, 0, 0);
}

// unpack 16 bf16 -> 16 f32 (two 16-B loads)
__device__ __forceinline__ f32x16 unpack16(const u16* p) {
  uint4 a = *(const uint4*)p, b = *(const uint4*)(p + 8);
  f32x16 r;
  r[0]  = __uint_as_float(a.x << 16); r[1]  = __uint_as_float(a.x & 0xffff0000u);
  r[2]  = __uint_as_float(a.y << 16); r[3]  = __uint_as_float(a.y & 0xffff0000u);
  r[4]  = __uint_as_float(a.z << 16); r[5]  = __uint_as_float(a.z & 0xffff0000u);
  r[6]  = __uint_as_float(a.w << 16); r[7]  = __uint_as_float(a.w & 0xffff0000u);
  r[8]  = __uint_as_float(b.x << 16); r[9]  = __uint_as_float(b.x & 0xffff0000u);
  r[10] = __uint_as_float(b.y << 16); r[11] = __uint_as_float(b.y & 0xffff0000u);
  r[12] = __uint_as_float(b.z << 16); r[13] = __uint_as_float(b.z & 0xffff0000u);
  r[14] = __uint_as_float(b.w << 16); r[15] = __uint_as_float(b.w & 0xffff0000u);
  return r;
}

// ---------------------------------------------------------------------------
// convert edge f32 [131072][256] -> bf16 tiled+swizzled [1024 rt][4 kc][128 r][64 k]
// element (r,k) stored at u16 idx r*64 + (k ^ ((r&7)*8)). NT loads: read-once
// stream, keep L3 free for E1/E2 (re-read 3x by fused_gate).
// ---------------------------------------------------------------------------
__global__ __launch_bounds__(256) void convert_edge(
    const float* __restrict__ src, u16* __restrict__ dst) {
  int g = blockIdx.x * 256 + threadIdx.x;
  int kg = g & 7, r = (g >> 3) & 127, kc = (g >> 10) & 3, rt = g >> 12;
  const float* s = src + ((long)(rt * 128 + r) * 256 + kc * 64 + kg * 8);
  f32x4 a = __builtin_nontemporal_load((const f32x4*)s);
  f32x4 b = __builtin_nontemporal_load((const f32x4*)(s + 4));
  u16x8 h;
  h[0] = f2bf(a[0]); h[1] = f2bf(a[1]); h[2] = f2bf(a[2]); h[3] = f2bf(a[3]);
  h[4] = f2bf(b[0]); h[5] = f2bf(b[1]); h[6] = f2bf(b[2]); h[7] = f2bf(b[3]);
  u16* d = dst + (long)rt * 65536 + kc * 16384 + r * 64 + (kg ^ (r & 7)) * 8;
  __builtin_nontemporal_store(h, (u16x8*)d);
}

// ---------------------------------------------------------------------------
// Edge GEMM: E[131072 x 512] = A_tiled(bf16) * Bt_tiled(bf16)^T, K=256.
// 128x128 tile, 4 waves, global_load_lds, swizzled LDS.
// XCD-aware block swizzle: the 4 ct-blocks of one rt land on the SAME XCD in
// adjacent rounds -> A tile served from that XCD's L2 (1x HBM not 4x).
// ---------------------------------------------------------------------------
__global__ __launch_bounds__(256) void gemm_edge(
    const u16* __restrict__ A, const u16* __restrict__ Bt,
    u16* __restrict__ E) {
  __shared__ __align__(16) u16 Asm[8192];
  __shared__ __align__(16) u16 Bsm[8192];
  const int tid = threadIdx.x, lane = tid & 63, w = tid >> 6;
  const int m = lane & 15, q = lane >> 4;
  const int p = blockIdx.x;
  const int sidx = p >> 3, xcd = p & 7;
  const int rt = (sidx >> 2) * 8 + xcd;   // same rt for 4 adjacent same-XCD slots
  const int ct = sidx & 3;
  const int wrow = (w & 1) * 64, wcol = (w >> 1) * 64;
  const char* Ab = (const char*)A + (long)rt * 131072;
  const char* Bb = (const char*)Bt + (long)ct * 65536;
  f32x4 acc[4][4];
#pragma unroll
  for (int r = 0; r < 4; ++r)
#pragma unroll
    for (int c = 0; c < 4; ++c) acc[r][c] = (f32x4){0.f, 0.f, 0.f, 0.f};

  for (int kc = 0; kc < 4; ++kc) {
#pragma unroll
    for (int t = 0; t < 4; ++t) {
      glds16(Ab + kc * 32768 + t * 4096 + tid * 16,
             (char*)Asm + t * 4096 + tid * 16);
      glds16(Bb + kc * 16384 + t * 4096 + tid * 16,
             (char*)Bsm + t * 4096 + tid * 16);
    }
    __syncthreads();
#pragma unroll
    for (int s = 0; s < 2; ++s) {
      const int ko2 = (s * 32 + q * 8) * 2;
      bf16x8 av[4], bv[4];
#pragma unroll
      for (int r = 0; r < 4; ++r) {
        int row = wrow + r * 16 + m;
        av[r] = *(const bf16x8*)((const char*)Asm + row * 128 +
                                 (ko2 ^ ((row & 7) * 16)));
      }
#pragma unroll
      for (int c = 0; c < 4; ++c) {
        int col = wcol + c * 16 + m;
        bv[c] = *(const bf16x8*)((const char*)Bsm + col * 128 +
                                 (ko2 ^ ((col & 7) * 16)));
      }
#pragma unroll
      for (int r = 0; r < 4; ++r)
#pragma unroll
        for (int c = 0; c < 4; ++c)
          acc[r][c] = __builtin_amdgcn_mfma_f32_16x16x32_bf16(
              av[r], bv[c], acc[r][c], 0, 0, 0);
    }
    __syncthreads();
  }
#pragma unroll
  for (int r = 0; r < 4; ++r)
#pragma unroll
    for (int c = 0; c < 4; ++c)
#pragma unroll
      for (int g = 0; g < 4; ++g) {
        long gr = (long)rt * 128 + wrow + r * 16 + q * 4 + g;
        int gc = ct * 128 + wcol + c * 16 + m;
        E[gr * 512 + gc] = f2bf(acc[r][c][g]);
      }
}

// ---------------------------------------------------------------------------
// Generic small GEMM (f32 A): C[M x Ntot] = A[M x K] * Bt[Ntot x K]^T
// ROWS=64 tile x 256 cols, 4 waves (each 64x64).
// MODE 0: f32 C. MODE 1: bf16 C. MODE 2: split — gc<256 -> relu to Cv(f32),
// gc>=256 -> raw to C2 (compact 256-wide).
// ---------------------------------------------------------------------------
template<int K, int MODE>
__global__ __launch_bounds__(256) void gemm_mfma(
    const float* __restrict__ A, const u16* __restrict__ Bt,
    void* __restrict__ Cv, float* __restrict__ C2, int Ntot) {
  constexpr int LD = 72;
  __shared__ __align__(16) u16 Asm[64 * LD];
  __shared__ __align__(16) u16 Bsm[256 * LD];
  const int tid = threadIdx.x;
  const int lane = tid & 63;
  const int w = tid >> 6;
  const int m = lane & 15;
  const int q = lane >> 4;
  const int wcol = w * 64;
  const long rowbase = (long)blockIdx.x * 64;
  const long colbase = (long)blockIdx.y * 256;
  f32x4 acc[4][4];
#pragma unroll
  for (int r = 0; r < 4; ++r)
#pragma unroll
    for (int c = 0; c < 4; ++c) acc[r][c] = (f32x4){0.f, 0.f, 0.f, 0.f};

  for (int kc = 0; kc < K / 64; ++kc) {
    const int kb = kc * 64;
#pragma unroll
    for (int it = 0; it < 4; ++it) {
      int f = it * 256 + tid;
      int r = f >> 4, c4 = (f & 15) * 4;
      float4 v = *(const float4*)(A + (rowbase + r) * K + kb + c4);
      ushort4 h;
      h.x = f2bf(v.x); h.y = f2bf(v.y); h.z = f2bf(v.z); h.w = f2bf(v.w);
      *(ushort4*)&Asm[r * LD + c4] = h;
    }
#pragma unroll
    for (int it = 0; it < 8; ++it) {
      int f = it * 256 + tid;
      int c = f >> 3, k8 = (f & 7) * 8;
      *(uint4*)&Bsm[c * LD + k8] =
          *(const uint4*)(Bt + (colbase + c) * K + kb + k8);
    }
    __syncthreads();
#pragma unroll
    for (int s = 0; s < 2; ++s) {
      const int ko = s * 32 + q * 8;
      bf16x8 av[4], bv[4];
#pragma unroll
      for (int r = 0; r < 4; ++r)
        av[r] = *(const bf16x8*)&Asm[(r * 16 + m) * LD + ko];
#pragma unroll
      for (int c = 0; c < 4; ++c)
        bv[c] = *(const bf16x8*)&Bsm[(wcol + c * 16 + m) * LD + ko];
#pragma unroll
      for (int r = 0; r < 4; ++r)
#pragma unroll
        for (int c = 0; c < 4; ++c)
          acc[r][c] = __builtin_amdgcn_mfma_f32_16x16x32_bf16(
              av[r], bv[c], acc[r][c], 0, 0, 0);
    }
    __syncthreads();
  }
#pragma unroll
  for (int r = 0; r < 4; ++r)
#pragma unroll
    for (int c = 0; c < 4; ++c)
#pragma unroll
      for (int g = 0; g < 4; ++g) {
        long gr = rowbase + r * 16 + q * 4 + g;
        long gc = colbase + wcol + c * 16 + m;
        float v = acc[r][c][g];
        if (MODE == 1)      ((u16*)Cv)[gr * Ntot + gc] = f2bf(v);
        else if (MODE == 0) ((float*)Cv)[gr * Ntot + gc] = v;
        else {
          if (gc < 256) ((float*)Cv)[gr * 256 + gc] = fmaxf(v, 0.f);
          else          C2[gr * 256 + gc - 256] = v;
        }
      }
}

// ---------------------------------------------------------------------------
// Weight tables. BtE1/BtE2: tiled+swizzled [4 ct][4 kc][128 c][64 k].
// BtW0 [512][256], BtLoop [1536][256], BtFc3 [256][512].
// ---------------------------------------------------------------------------
__global__ __launch_bounds__(256) void prep_bt(
    const float* __restrict__ weight, const float* __restrict__ align_lin,
    const float* __restrict__ fuse1_w, const float* __restrict__ fuse2_w,
    const float* __restrict__ fc1_w0, const float* __restrict__ fc2_w0,
    const float* __restrict__ fc3_w,
    u16* BtE1, u16* BtE2, u16* BtW0, u16* BtLoop, u16* BtFc3) {
  int g = blockIdx.x * 256 + threadIdx.x;  // 0..917503
  if (g < 262144) {
    int t = g & 131071;
    int col = t >> 8, k = t & 255;
    float v;
    if (g < 131072)
      v = (col < 256) ? fuse1_w[(256 + k) * 256 + col]
                      : fc1_w0[(512 + k) * 256 + (col - 256)];
    else
      v = (col < 256) ? fuse2_w[(256 + k) * 256 + col]
                      : fc2_w0[(512 + k) * 256 + (col - 256)];
    int ct = col >> 7, cc = col & 127, kc = k >> 6, kk = k & 63;
    u16* dst = (g < 131072) ? BtE1 : BtE2;
    dst[ct * 32768 + kc * 8192 + cc * 64 + (kk ^ ((cc & 7) * 8))] = f2bf(v);
  } else if (g < 393216) {
    int t = g - 262144;
    int c = t >> 8, k = t & 255;
    float v = (c < 256) ? weight[k * 256 + c] : align_lin[k * 256 + (c - 256)];
    BtW0[t] = f2bf(v);
  } else if (g < 786432) {
    int t = g - 393216;
    int c = t >> 8, k = t & 255;
    int seg = c >> 8, cc = c & 255;
    float v;
    if      (seg == 0) v = fuse1_w[k * 256 + cc];
    else if (seg == 1) v = fuse2_w[k * 256 + cc];
    else if (seg == 2) v = fc1_w0[k * 256 + cc];
    else if (seg == 3) v = fc1_w0[(256 + k) * 256 + cc];
    else if (seg == 4) v = fc2_w0[k * 256 + cc];
    else               v = fc2_w0[(256 + k) * 256 + cc];
    BtLoop[t] = f2bf(v);
  } else {
    int t = g - 786432;
    int c = t >> 9, k = t & 511;
    BtFc3[t] = f2bf(fc3_w[k * 256 + c]);
  }
}

// ---------------------------------------------------------------------------
// SelfAlignment. 256 threads: phase 1 (tid<128) logits+softmax, phase 2 all
// 256 threads do the p @ text matvec (one d each).
// ---------------------------------------------------------------------------
__global__ __launch_bounds__(256) void align_kernel(
    const float* __restrict__ text, const float* __restrict__ Ta,
    const float* __restrict__ textmask, const float* __restrict__ align_bias,
    float* __restrict__ outss) {
  const int bi = blockIdx.x;
  const int b = bi >> 7;
  const int tid = threadIdx.x;
  __shared__ float ta[256];
  __shared__ float pr[128];
  __shared__ float red[128];
  ta[tid] = Ta[(long)bi * 256 + tid];
  __syncthreads();
  float e = 0.f;
  if (tid < 128) {
    const float* trow = text + (long)(b * 128 + tid) * 256;
    float dot = 0.f;
    for (int d = 0; d < 256; d += 4) {
      float4 t4 = *(const float4*)(trow + d);
      dot += t4.x * ta[d] + t4.y * ta[d + 1] + t4.z * ta[d + 2] + t4.w * ta[d + 3];
    }
    float logit = dot + (1.0f - textmask[b * 128 + tid]) * -1e20f;
    pr[tid] = logit;
    red[tid] = logit;
  }
  __syncthreads();
  for (int off = 64; off; off >>= 1) {
    if (tid < off) red[tid] = fmaxf(red[tid], red[tid + off]);
    __syncthreads();
  }
  float mx = red[0];
  __syncthreads();
  if (tid < 128) {
    e = __expf(pr[tid] - mx);
    red[tid] = e;
  }
  __syncthreads();
  for (int off = 64; off; off >>= 1) {
    if (tid < off) red[tid] += red[tid + off];
    __syncthreads();
  }
  float inv = 1.0f / red[0];
  __syncthreads();
  if (tid < 128) pr[tid] = e * inv;
  __syncthreads();
  const float mi = textmask[bi];
  float s = 0.f;
  const float* tcol = text + (long)b * 32768 + tid;
#pragma unroll 4
  for (int j = 0; j < 128; ++j) s += pr[j] * tcol[j * 256];
  outss[(long)bi * 256 + tid] = s * mi + align_bias[tid];
}

// ---------------------------------------------------------------------------
// Fused gate/aggregate partials. grid 4096: bi = blk>>2, jc = blk&3 (32 j's).
// 128 thr = 2 waves; wave w: j = jc*32 + w*16 + t*4 + g16, lane owns 16 d's.
// __launch_bounds__(128, 2): VGPR cap 256 — the (128,4) variant capped at 64
// VGPRs and spilled ~470 MB of scratch traffic (R3 post-mortem). Never bound
// occupancy above the register budget.
// ---------------------------------------------------------------------------
__global__ __launch_bounds__(128, 2) void fused_gate(
    const u16* __restrict__ E1, const u16* __restrict__ E2,
    const float* __restrict__ P, const float* __restrict__ adj1,
    const float* __restrict__ adj2, const float* __restrict__ fc1w1,
    const float* __restrict__ fc1b1, const float* __restrict__ fc2w1,
    const float* __restrict__ fc2b1, float* __restrict__ OUP,
    float* __restrict__ DAP) {
  const int tid = threadIdx.x, lane = tid & 63, w = tid >> 6;
  const int g16 = lane >> 4, l16 = lane & 15;
  const int blk = blockIdx.x;
  const int bi = blk >> 2, jc = blk & 3;
  const int b = bi >> 7;
  const int db = l16 * 16;
  const long rowi = (long)bi * 1536;
  const f32x16 w1v = *(const f32x16*)(fc1w1 + db);
  const f32x16 w2v = *(const f32x16*)(fc2w1 + db);
  const f32x16 ti1 = *(const f32x16*)(P + rowi + 512 + db);
  const f32x16 ti2 = *(const f32x16*)(P + rowi + 1024 + db);
  const float b1 = fc1b1[0], b2 = fc2b1[0];
  const long ebase = (long)bi * 65536;
  const int abase = bi * 128;
  f32x16 acc1, acc2;
#pragma unroll
  for (int dd = 0; dd < 16; ++dd) { acc1[dd] = 0.f; acc2[dd] = 0.f; }
  float da1 = 0.f, da2 = 0.f;

  for (int t = 0; t < 4; ++t) {
    const int j = jc * 32 + w * 16 + t * 4 + g16;
    const long er = ebase + (long)j * 512;
    const long rowj = (long)(b * 128 + j) * 1536;
    f32x16 e1cf = unpack16(E1 + er + 256 + db);
    f32x16 e2cf = unpack16(E2 + er + 256 + db);
    f32x16 tj1 = *(const f32x16*)(P + rowj + 768 + db);
    f32x16 tj2 = *(const f32x16*)(P + rowj + 1280 + db);
    float a1 = adj1[abase + j], a2 = adj2[abase + j];
    float z1 = 0.f, z2 = 0.f;
#pragma unroll
    for (int dd = 0; dd < 16; ++dd) {
      z1 += fmaxf(ti1[dd] + tj1[dd] + e1cf[dd], 0.f) * w1v[dd];
      z2 += fmaxf(ti2[dd] + tj2[dd] + e2cf[dd], 0.f) * w2v[dd];
    }
#pragma unroll
    for (int off = 1; off < 16; off <<= 1) {
      z1 += __shfl_xor(z1, off);
      z2 += __shfl_xor(z2, off);
    }
    float s1 = a1 / (1.f + __expf(-(z1 + b1)));
    float s2 = a2 / (1.f + __expf(-(z2 + b2)));
    f32x16 e1ff = unpack16(E1 + er + db);
    f32x16 e2ff = unpack16(E2 + er + db);
    f32x16 of1 = *(const f32x16*)(P + rowj + db);
    f32x16 of2 = *(const f32x16*)(P + rowj + 256 + db);
#pragma unroll
    for (int dd = 0; dd < 16; ++dd) {
      acc1[dd] += s1 * fmaxf(of1[dd] + e1ff[dd], 0.f);
      acc2[dd] += s2 * fmaxf(of2[dd] + e2ff[dd], 0.f);
    }
    da1 += a1;
    da2 += a2;
  }

  __shared__ float redA[8][260];
  __shared__ float redB[8][260];
  __shared__ float dA[8], dB[8];
  const int pidx = w * 4 + g16;
#pragma unroll
  for (int v = 0; v < 4; ++v) {
    *(float4*)&redA[pidx][db + v * 4] =
        make_float4(acc1[v*4], acc1[v*4+1], acc1[v*4+2], acc1[v*4+3]);
    *(float4*)&redB[pidx][db + v * 4] =
        make_float4(acc2[v*4], acc2[v*4+1], acc2[v*4+2], acc2[v*4+3]);
  }
  if (l16 == 0) { dA[pidx] = da1; dB[pidx] = da2; }
  __syncthreads();
#pragma unroll
  for (int h = 0; h < 2; ++h) {
    int col = h * 128 + tid;
    float o1 = 0.f, o2 = 0.f;
#pragma unroll
    for (int pp = 0; pp < 8; ++pp) {
      o1 += redA[pp][col];
      o2 += redB[pp][col];
    }
    OUP[(long)blk * 512 + col] = o1;
    OUP[(long)blk * 512 + 256 + col] = o2;
  }
  if (tid == 0) {
    float d1 = 0.f, d2 = 0.f;
#pragma unroll
    for (int pp = 0; pp < 8; ++pp) { d1 += dA[pp]; d2 += dB[pp]; }
    DAP[blk * 2] = d1;
    DAP[blk * 2 + 1] = d2;
  }
}

// ---------------------------------------------------------------------------
// Merge the 4 j-chunk partials: OU12[bi][512] = (sum_c OUP)/(1+sum_c DAP)
// ---------------------------------------------------------------------------
__global__ __launch_bounds__(256) void merge_ou(
    const float* __restrict__ OUP, const float* __restrict__ DAP,
    float* __restrict__ OU12) {
  const int bi = blockIdx.x, tid = threadIdx.x;
  const long base = (long)bi * 4 * 512;
  float d1 = 1.f + DAP[bi*8+0] + DAP[bi*8+2] + DAP[bi*8+4] + DAP[bi*8+6];
  float d2 = 1.f + DAP[bi*8+1] + DAP[bi*8+3] + DAP[bi*8+5] + DAP[bi*8+7];
#pragma unroll
  for (int h = 0; h < 2; ++h) {
    int col = h * 256 + tid;
    float o = OUP[base + col] + OUP[base + 512 + col] +
              OUP[base + 1024 + col] + OUP[base + 1536 + col];
    OU12[(long)bi * 512 + col] = o / ((col < 256) ? d1 : d2);
  }
}

// ---------------------------------------------------------------------------
// out = layernorm(relu(Y) + prev + bias) * gamma + beta
// ---------------------------------------------------------------------------
__global__ __launch_bounds__(256) void ln_kernel(
    const float* __restrict__ Y, const float* __restrict__ prev,
    const float* __restrict__ bias, const float* __restrict__ gamma,
    const float* __restrict__ beta, float* __restrict__ dst) {
  const int row = blockIdx.x, tid = threadIdx.x, lane = tid & 63, w = tid >> 6;
  const long idx = (long)row * 256 + tid;
  float v = fmaxf(Y[idx], 0.f) + prev[idx] + bias[tid];
  float s = v;
#pragma unroll
  for (int off = 32; off; off >>= 1) s += __shfl_xor(s, off);
  __shared__ float wsA[4], wsB[4];
  if (lane == 0) wsA[w] = s;
  __syncthreads();
  float mean = (wsA[0] + wsA[1] + wsA[2] + wsA[3]) * (1.0f / 256.0f);
  float c = v - mean;
  float s2 = c * c;
#pragma unroll
  for (int off = 32; off; off >>= 1) s2 += __shfl_xor(s2, off);
  if (lane == 0) wsB[w] = s2;
  __syncthreads();
  float var = (wsB[0] + wsB[1] + wsB[2] + wsB[3]) * (1.0f / 256.0f);
  dst[idx] = c * rsqrtf(var + 1e-5f) * gamma[tid] + beta[tid];
}

// ---------------------------------------------------------------------------
extern "C" void kernel_launch(void* const* d_in, const int* in_sizes, int n_in,
                              void* d_out, int out_size, void* d_ws, size_t ws_size,
                              hipStream_t stream) {
  const float* text      = (const float*)d_in[0];
  const float* adj1      = (const float*)d_in[1];
  const float* adj2      = (const float*)d_in[2];
  const float* edge1     = (const float*)d_in[3];
  const float* edge2     = (const float*)d_in[4];
  const float* textmask  = (const float*)d_in[5];
  const float* weight    = (const float*)d_in[6];
  const float* bias      = (const float*)d_in[7];
  const float* gamma     = (const float*)d_in[8];
  const float* beta      = (const float*)d_in[9];
  const float* fuse1_w   = (const float*)d_in[10];
  const float* fuse2_w   = (const float*)d_in[11];
  const float* fc3_w     = (const float*)d_in[12];
  const float* fc1_w0    = (const float*)d_in[13];
  const float* fc1_w1    = (const float*)d_in[14];
  const float* fc1_b1    = (const float*)d_in[15];
  const float* fc2_w0    = (const float*)d_in[16];
  const float* fc2_w1    = (const float*)d_in[17];
  const float* fc2_b1    = (const float*)d_in[18];
  const float* align_lin = (const float*)d_in[19];
  const float* align_bias= (const float*)d_in[20];
  float* outF = (float*)d_out;  // out: [0,262144), outss: [262144,524288)

  char* w8 = (char*)d_ws;
  u16* Ax   = (u16*)w8;                       // 64 MB region (dual-use)
  u16* E1   = (u16*)(w8 + 67108864);          // 128 MB
  u16* E2   = (u16*)(w8 + 201326592);         // 128 MB
  u16* BtE1 = (u16*)(w8 + 335544320);
  u16* BtE2 = BtE1 + 131072;
  u16* BtW0 = BtE2 + 131072;
  u16* BtLoop = BtW0 + 131072;                // 1536 x 256
  u16* BtFc3  = BtLoop + 393216;              // 256 x 512
  // f32 buffers inside the Ax region (dead after edge GEMMs)
  float* P    = (float*)w8;                   // 1024 x 1536 (6 MB)
  float* Ta   = P + 1572864;                  // 1024 x 256 (1 MB)
  float* OU12 = Ta + 262144;                  // 1024 x 512 (2 MB)
  float* outb = OU12 + 524288;                // 1024 x 256 (1 MB)
  float* Yb   = outb + 262144;                // 1024 x 256 (1 MB)
  float* OUP  = Yb + 262144;                  // 4096 x 512 (8 MB)
  float* DAP  = OUP + 2097152;                // 4096 x 2

  // 1) weight tables
  prep_bt<<<3584, 256, 0, stream>>>(weight, align_lin, fuse1_w, fuse2_w,
                                    fc1_w0, fc2_w0, fc3_w,
                                    BtE1, BtE2, BtW0, BtLoop, BtFc3);
  // 2) edge projections (loop-invariant)
  convert_edge<<<16384, 256, 0, stream>>>(edge1, Ax);
  gemm_edge<<<4096, 256, 0, stream>>>(Ax, BtE1, E1);
  convert_edge<<<16384, 256, 0, stream>>>(edge2, Ax);
  gemm_edge<<<4096, 256, 0, stream>>>(Ax, BtE2, E2);
  // 3) split GEMM: outb = relu(text@weight), Ta = text@align_lin
  gemm_mfma<256, 2><<<dim3(16, 2), 256, 0, stream>>>(text, BtW0, outb, Ta, 512);
  // 4) self-alignment -> outss
  align_kernel<<<1024, 256, 0, stream>>>(text, Ta, textmask, align_bias,
                                         outF + 262144);
  // 5) K = 3 GCN iterations
  for (int it = 0; it < 3; ++it) {
    gemm_mfma<256, 0><<<dim3(16, 6), 256, 0, stream>>>(outb, BtLoop, P, nullptr, 1536);
    fused_gate<<<4096, 128, 0, stream>>>(E1, E2, P, adj1, adj2, fc1_w1, fc1_b1,
                                         fc2_w1, fc2_b1, OUP, DAP);
    merge_ou<<<1024, 256, 0, stream>>>(OUP, DAP, OU12);
    gemm_mfma<512, 0><<<dim3(16, 1), 256, 0, stream>>>(OU12, BtFc3, Yb, nullptr, 256);
    ln_kernel<<<1024, 256, 0, stream>>>(Yb, outb, bias, gamma, beta,
                                        (it == 2) ? outF : outb);
  }
}